// Round 6
// baseline (777.463 us; speedup 1.0000x reference)
//
#include <hip/hip_runtime.h>
#include <cstdint>
#include <cstddef>

// ---------------------------------------------------------------------------
// MultiLayer bidirectional TreeLSTM, N=4096 heap tree, H=512, L=2.
// R12: mm_pre8 phase restructured to the m201 placement: ds_reads issued
// BEFORE the barrier (overlap barrier drain + MFMA stagger), one unit staged
// per phase, uniform counted s_waitcnt vmcnt(4) (never drains to 0 in steady
// state). Wait-chain verified: P3's vmcnt(4) covers U0',V0' for next-tile P0
// reads; P0 covers V1'; P1 covers U1'. Fragments double-buffered (A0/A1/B0/
// B1). Everything else identical to R11 (776 us).
// ---------------------------------------------------------------------------

#define HDIM 512
#define ZROW 4096
#define NCAT 6656   // 512 px_f | 3072 x2_f | 512 px_b | 2560 x2_b

typedef _Float16 f16;
typedef f16   f16x8 __attribute__((ext_vector_type(8)));
typedef float f32x4 __attribute__((ext_vector_type(4)));

__device__ __forceinline__ float sigm(float x) { return 1.0f / (1.0f + expf(-x)); }

// direct global->LDS DMA, 16 B per lane; LDS dest linear (base + lane*16).
__device__ __forceinline__ void glds16(const f16* g, f16* l)
{
    __builtin_amdgcn_global_load_lds(
        (const __attribute__((address_space(1))) void*)g,
        (__attribute__((address_space(3))) void*)l,
        16, 0, 0);
}

#define VM4()   asm volatile("s_waitcnt vmcnt(4)" ::: "memory")
#define VM0()   asm volatile("s_waitcnt vmcnt(0)" ::: "memory")
#define BAR()   __builtin_amdgcn_s_barrier()
#define SP1()   __builtin_amdgcn_s_setprio(1)
#define SP0()   __builtin_amdgcn_s_setprio(0)

__device__ __forceinline__ void cvt8s(const float* __restrict__ s, f16* __restrict__ d)
{
    float4 v0 = ((const float4*)s)[0];
    float4 v1 = ((const float4*)s)[1];
    f16x8 o;
    o[0] = (f16)v0.x; o[1] = (f16)v0.y; o[2] = (f16)v0.z; o[3] = (f16)v0.w;
    o[4] = (f16)v1.x; o[5] = (f16)v1.y; o[6] = (f16)v1.z; o[7] = (f16)v1.w;
    *(f16x8*)d = o;
}

__global__ __launch_bounds__(256) void cvt16(
    const float* __restrict__ s, f16* __restrict__ d, int n8)
{
    int i = blockIdx.x * 256 + threadIdx.x;
    if (i >= n8) return;
    cvt8s(s + (size_t)i * 8, d + (size_t)i * 8);
}

// ---------------------------------------------------------------------------
// One-launch per-layer weight prep (R10-proven).
// ---------------------------------------------------------------------------
__global__ __launch_bounds__(256) void prep_layer(
    const float* __restrict__ fWp, const float* __restrict__ fWx,
    const float* __restrict__ bWp, const float* __restrict__ bWx,
    const float* __restrict__ fWl, const float* __restrict__ fWr,
    const float* __restrict__ bWh,
    const float* __restrict__ fbp, const float* __restrict__ fbx,
    const float* __restrict__ bbp, const float* __restrict__ bbx,
    f16* __restrict__ Wcat, f16* __restrict__ Wlr, f16* __restrict__ Wh,
    float* __restrict__ biascat)
{
    const int bid = blockIdx.x;
    const int t   = threadIdx.x;
    if (bid < 256) {
        int i = bid * 256 + t;
        cvt8s(fWp + (size_t)i * 8, Wcat + (size_t)i * 8);
    } else if (bid < 1792) {
        int i = (bid - 256) * 256 + t;
        cvt8s(fWx + (size_t)i * 8, Wcat + (size_t)512 * 1024 + (size_t)i * 8);
    } else if (bid < 2048) {
        int i = (bid - 1792) * 256 + t;
        cvt8s(bWp + (size_t)i * 8, Wcat + (size_t)3584 * 1024 + (size_t)i * 8);
    } else if (bid < 3328) {
        int i = (bid - 2048) * 256 + t;
        cvt8s(bWx + (size_t)i * 8, Wcat + (size_t)4096 * 1024 + (size_t)i * 8);
    } else if (bid < 4864) {
        int i = (bid - 3328) * 256 + t;        // over 3072*1024/8
        int col8 = (i * 8) & 1023;
        int row  = (i * 8) >> 10;
        const float* s = (col8 < HDIM) ? (fWl + (size_t)row * HDIM + col8)
                                       : (fWr + (size_t)row * HDIM + col8 - HDIM);
        int np = (row & 511) * 6 + (row >> 9);
        cvt8s(s, Wlr + (size_t)np * 1024 + col8);
    } else if (bid < 5504) {
        int i = (bid - 4864) * 256 + t;        // over 2560*512/8
        int col8 = (i * 8) & 511;
        int row  = (i * 8) >> 9;
        int np = (row & 511) * 5 + (row >> 9);
        cvt8s(bWh + (size_t)row * HDIM + col8, Wh + (size_t)np * HDIM + col8);
    } else {
        int i = (bid - 5504) * 256 + t;
        if (i >= NCAT) return;
        float v;
        if (i < 512) v = fbp[i];
        else if (i < 3584) v = fbx[i - 512];
        else if (i < 4096) v = bbp[i - 3584];
        else v = bbx[i - 4096];
        biascat[i] = v;
    }
}

__global__ void zero_slots(f16* H, float* cbf, float* cbb)
{
    int t = threadIdx.x;  // 1024 threads
    H[(size_t)ZROW * 1024 + t] = (f16)0.0f;
    if (t < HDIM) {
        cbf[(size_t)ZROW * HDIM + t] = 0.0f;
        cbb[(size_t)ZROW * HDIM + t] = 0.0f;
    }
}

// ---------------------------------------------------------------------------
// Precompute GEMM, 256^2 phase-pipelined: C[M,N] = A[M,K]@W[N,K]^T + bias.
// 512 threads = 8 waves (wr=wid>>2 in M, wc=wid&3 in N); per-wave C 128x64.
// LDS: lds[buf][op][256*64] f16, buf = K-tile parity (BK=64), 128 KiB.
// Per K-tile T, 4 phases (quadrants): (0,0),(0,1),(1,1),(1,0). Phase body:
//   {ds_reads for THIS quadrant; stage 1 unit of T+1; vmcnt(4); s_barrier;
//    setprio(1); 16 MFMA; setprio(0)}
// Reads precede the barrier -> latency drains during barrier wait (m201
// placement, the m196-proven interleave). Stage order U0,V0,V1,U1; uniform
// vmcnt(4): each fresh unit is covered by a vmcnt >=1 barrier before its
// first read. Swizzle both-sides (rule #21): src seg^(row&7), read same XOR.
// ---------------------------------------------------------------------------
__global__ __launch_bounds__(512) void mm_pre8(
    const f16* __restrict__ A, const f16* __restrict__ W,
    const float* __restrict__ bias, f16* __restrict__ C, int N, int K)
{
    __shared__ __align__(16) f16 lds[2][2][16384];   // [buf][A=0/B=1], 128 KiB
    const int t   = threadIdx.x;
    const int L   = t & 63;
    const int wid = t >> 6;
    const int wr  = wid >> 2;        // 0..1  (M)
    const int wc  = wid & 3;         // 0..3  (N)
    const int fr  = L & 15;
    const int fq  = L >> 4;
    // staging geometry
    const int srow = t >> 3;                          // 0..63
    const int cs   = (((t & 7) ^ (srow & 7)) << 3);   // swizzled global col (f16)
    const int vrow = ((srow >> 5) << 6) + (srow & 31);
    const int bB0  = (srow >= 32) ? 2048 : 0;
    const f16* Ag = A + (size_t)(blockIdx.y * 256) * K + cs;
    const f16* Bg = W + (size_t)(blockIdx.x * 256) * K + cs;
    // frag-read swizzled col offsets (f16 units), ks = 0/1
    const int xa0 = ((fq)     ^ (fr & 7)) << 3;
    const int xa1 = ((4 + fq) ^ (fr & 7)) << 3;

#define STG_A(nb, T, u)                                                      \
    do {                                                                     \
        glds16(Ag + (size_t)(srow + (u) * 64) * K + (T) * 64,                \
               &lds[nb][0][(u) * 4096 + t * 8]);                             \
        glds16(Ag + (size_t)(srow + (u) * 64 + 128) * K + (T) * 64,          \
               &lds[nb][0][(u) * 4096 + 8192 + t * 8]);                      \
    } while (0)
#define STG_B(nb, T, v)                                                      \
    do {                                                                     \
        glds16(Bg + (size_t)(vrow + (v) * 32) * K + (T) * 64,                \
               &lds[nb][1][(v) * 2048 + bB0 + t * 8]);                       \
        glds16(Bg + (size_t)(vrow + (v) * 32 + 128) * K + (T) * 64,          \
               &lds[nb][1][(v) * 2048 + bB0 + 8192 + t * 8]);                \
    } while (0)

    f32x4 acc[8][4] = {};
    f16x8 a0f[4][2], a1f[4][2], b0f[2][2], b1f[2][2];

#define LDA(AF, Ar, mh)                                                            \
    do {                                                                           \
        _Pragma("unroll") for (int i2 = 0; i2 < 4; ++i2) {                         \
            AF[i2][0] = *(const f16x8*)((Ar) + ((mh) * 64 + i2 * 16) * 64 + xa0);  \
            AF[i2][1] = *(const f16x8*)((Ar) + ((mh) * 64 + i2 * 16) * 64 + xa1);  \
        }                                                                          \
    } while (0)
#define LDB(BF, Br, nh)                                                            \
    do {                                                                           \
        _Pragma("unroll") for (int j2 = 0; j2 < 2; ++j2) {                         \
            BF[j2][0] = *(const f16x8*)((Br) + ((nh) * 32 + j2 * 16) * 64 + xa0);  \
            BF[j2][1] = *(const f16x8*)((Br) + ((nh) * 32 + j2 * 16) * 64 + xa1);  \
        }                                                                          \
    } while (0)
#define MF(AF, BF, mh, nh)                                                         \
    do {                                                                           \
        _Pragma("unroll") for (int ks = 0; ks < 2; ++ks)                           \
        _Pragma("unroll") for (int i2 = 0; i2 < 4; ++i2)                           \
        _Pragma("unroll") for (int j2 = 0; j2 < 2; ++j2)                           \
            acc[(mh) * 4 + i2][(nh) * 2 + j2] =                                    \
                __builtin_amdgcn_mfma_f32_16x16x32_f16(                            \
                    AF[i2][ks], BF[j2][ks],                                        \
                    acc[(mh) * 4 + i2][(nh) * 2 + j2], 0, 0, 0);                   \
    } while (0)

    const int NT = K >> 6;
    // prologue: stage tile 0 fully, drain, barrier.
    STG_A(0, 0, 0); STG_B(0, 0, 0); STG_B(0, 0, 1); STG_A(0, 0, 1);
    VM0();
    BAR();

    for (int T = 0; T < NT; ++T) {
        const int cb = T & 1, nb = cb ^ 1;
        const bool pf = (T + 1 < NT);
        const f16* Ar = &lds[cb][0][(wr * 128 + fr) * 64];
        const f16* Br = &lds[cb][1][(wc * 64 + fr) * 64];
        // ---- P0: quadrant (0,0); reads A0,B0; stage U0(T+1) ----
        LDA(a0f, Ar, 0); LDB(b0f, Br, 0);
        if (pf) STG_A(nb, T + 1, 0);
        VM4(); BAR();
        SP1(); MF(a0f, b0f, 0, 0); SP0();
        // ---- P1: quadrant (0,1); reads B1; stage V0(T+1) ----
        LDB(b1f, Br, 1);
        if (pf) STG_B(nb, T + 1, 0);
        VM4(); BAR();
        SP1(); MF(a0f, b1f, 0, 1); SP0();
        // ---- P2: quadrant (1,1); reads A1; stage V1(T+1) ----
        LDA(a1f, Ar, 1);
        if (pf) STG_B(nb, T + 1, 1);
        VM4(); BAR();
        SP1(); MF(a1f, b1f, 1, 1); SP0();
        // ---- P3: quadrant (1,0); no reads; stage U1(T+1) ----
        if (pf) STG_A(nb, T + 1, 1);
        VM4(); BAR();
        SP1(); MF(a1f, b0f, 1, 0); SP0();
    }
#undef STG_A
#undef STG_B
#undef LDA
#undef LDB
#undef MF

    // C/D layout: col = lane&15, row = (lane>>4)*4 + reg  [m89-verified]
    const int gr0 = blockIdx.y * 256 + wr * 128 + fq * 4;
    const int gc0 = blockIdx.x * 256 + wc * 64 + fr;
#pragma unroll
    for (int j = 0; j < 4; ++j) {
        const int gc = gc0 + j * 16;
        const float bj = bias[gc];
#pragma unroll
        for (int i = 0; i < 8; ++i) {
            const int gr = gr0 + i * 16;
#pragma unroll
            for (int rr = 0; rr < 4; ++rr)
                C[(size_t)(gr + rr) * N + gc] = (f16)(acc[i][j][rr] + bj);
        }
    }
}

// ---------------------------------------------------------------------------
// Fused stage kernel: GEMM (gathered A rows) + LSTM cell math + H/c writes,
// one launch per merged fwd/bwd stage pair. (R8-proven form.)
// ---------------------------------------------------------------------------
__global__ __launch_bounds__(256) void stage_fused(
    const f16* __restrict__ Wlr, const f16* __restrict__ Wh,
    f16* H, const f16* __restrict__ PX,
    const int* __restrict__ lc, const int* __restrict__ rc,
    const int* __restrict__ par,
    int fbase, int fm, int bbase, int bm,
    float* __restrict__ cbf, float* __restrict__ cbb,
    float* out32,
    const float* __restrict__ bl, const float* __restrict__ br,
    const float* __restrict__ bh)
{
    __shared__ __align__(16) char smem[57344];
    f16*   Ab0 = (f16*)smem;             // [2][128*64] = 32 KB
    f16*   Bb0 = (f16*)(smem + 32768);   // [2][96*64] or [2][80*64]
    float* Sg  = (float*)smem;           // epilogue scoreboard (aliases staging)

    const int t   = threadIdx.x;
    const int L   = t & 63;
    const int w   = t >> 6;
    const int fr  = L & 15;
    const int fq  = L >> 4;
    const int rch = L >> 3;                       // row within 8-row chunk
    const int cs  = (((L & 7) ^ rch) << 3);       // swizzled source col (f16, <64)
    const int fsw = (fr & 7) << 3;                // frag-read swizzle (f16 units)
    const int nfB = ((fm + 127) >> 7) * 32;

    if ((int)blockIdx.x < nfB) {
        // ----------------- forward (leaves-to-root) tile -----------------
        const int by = blockIdx.x >> 5;
        const int bx = blockIdx.x & 31;
        const int wm = (w & 1) << 6;
        const int wn = (w >> 1) * 48;

        const f16* aLo[4]; const f16* aHi[4];
#pragma unroll
        for (int cc = 0; cc < 4; ++cc) {
            int g  = by * 128 + (w * 4 + cc) * 8 + rch;
            int n1 = ZROW, n2 = ZROW;
            if (g < fm) { n1 = lc[fbase + g]; n2 = rc[fbase + g]; }
            aLo[cc] = H + (size_t)n1 * 1024 + cs;
            aHi[cc] = H + (size_t)n2 * 1024 + cs - HDIM;
        }
        const f16* bsrc[3];
#pragma unroll
        for (int cc = 0; cc < 3; ++cc)
            bsrc[cc] = Wlr + (size_t)(bx * 96 + (w * 3 + cc) * 8 + rch) * 1024 + cs;

        f32x4 acc[4][3] = {};
#define STGF(sel, k0)                                                        \
        do {                                                                 \
            const bool hiK = (k0) >= HDIM;                                   \
            _Pragma("unroll")                                                \
            for (int cc = 0; cc < 4; ++cc)                                   \
                glds16((hiK ? aHi[cc] : aLo[cc]) + (k0),                     \
                       Ab0 + (sel) * 8192 + (w * 4 + cc) * 512 + L * 8);     \
            _Pragma("unroll")                                                \
            for (int cc = 0; cc < 3; ++cc)                                   \
                glds16(bsrc[cc] + (k0),                                      \
                       Bb0 + (sel) * 6144 + (w * 3 + cc) * 512 + L * 8);     \
        } while (0)

        STGF(0, 0);
        __syncthreads();
        int cur = 0;
        for (int tt = 0; tt < 16; ++tt) {
            if (tt + 1 < 16) STGF(cur ^ 1, (tt + 1) * 64);
            const f16* Ac = Ab0 + cur * 8192;
            const f16* Bc = Bb0 + cur * 6144;
            f16x8 af[4][2], bg[3][2];
#pragma unroll
            for (int i = 0; i < 4; ++i)
#pragma unroll
                for (int ks = 0; ks < 2; ++ks)
                    af[i][ks] = *(const f16x8*)(Ac + (wm + i * 16 + fr) * 64
                                + ((((ks * 4 + fq) << 3) ^ fsw)));
#pragma unroll
            for (int j = 0; j < 3; ++j)
#pragma unroll
                for (int ks = 0; ks < 2; ++ks)
                    bg[j][ks] = *(const f16x8*)(Bc + (wn + j * 16 + fr) * 64
                                + ((((ks * 4 + fq) << 3) ^ fsw)));
#pragma unroll
            for (int ks = 0; ks < 2; ++ks)
#pragma unroll
                for (int i = 0; i < 4; ++i)
#pragma unroll
                    for (int j = 0; j < 3; ++j)
                        acc[i][j] = __builtin_amdgcn_mfma_f32_16x16x32_f16(
                            af[i][ks], bg[j][ks], acc[i][j], 0, 0, 0);
            __syncthreads();
            cur ^= 1;
        }
#undef STGF
        // epilogue: acc -> Sg[128][100]
#pragma unroll
        for (int i = 0; i < 4; ++i)
#pragma unroll
            for (int j = 0; j < 3; ++j)
#pragma unroll
                for (int rr = 0; rr < 4; ++rr)
                    Sg[(wm + i * 16 + fq * 4 + rr) * 100 + wn + j * 16 + fr]
                        = acc[i][j][rr];
        __syncthreads();
        const int rmax = fm - by * 128;
        const int j0 = bx * 16;
        for (int cc = 0; cc < 8; ++cc) {
            int cell = t + cc * 256;
            int r = cell >> 4, j = cell & 15;
            if (r >= rmax) break;                 // r strictly increases with cc
            int node = fbase + by * 128 + r;
            int jj = j0 + j;
            const f16* pxr = PX + (size_t)node * NCAT;
            float g[6];
#pragma unroll
            for (int q = 0; q < 6; ++q)
                g[q] = (float)pxr[HDIM + q * HDIM + jj] + bl[q * HDIM + jj]
                     + br[q * HDIM + jj] + Sg[r * 100 + j * 6 + q];
            int lcn = lc[node], rcn = rc[node];
            float clv = cbf[(size_t)lcn * HDIM + jj];
            float crv = cbf[(size_t)rcn * HDIM + jj];
            float i_ = sigm(g[0]), o_ = sigm(g[1]), fl_ = sigm(g[2]), fr_ = sigm(g[3]);
            float u_ = tanhf(g[4]), r_ = sigm(g[5]);
            float c  = i_ * u_ + fl_ * clv + fr_ * crv;
            float hc = o_ * tanhf(c);
            float px = (float)pxr[jj];
            float hf = r_ * hc + (1.0f - r_) * px;
            cbf[(size_t)node * HDIM + jj] = c;
            H[(size_t)node * 1024 + jj] = (f16)hf;
            if (out32) out32[(size_t)node * 1024 + jj] = hf;
        }
    } else {
        // ----------------- backward (root-to-leaves) tile ----------------
        const int b2 = blockIdx.x - nfB;
        const int by = b2 >> 5;
        const int bx = b2 & 31;
        const int wm = w * 32;                    // 4 waves x 32 rows

        const f16* asrc[4];
#pragma unroll
        for (int cc = 0; cc < 4; ++cc) {
            int g = by * 128 + (w * 4 + cc) * 8 + rch;
            int n1 = ZROW;
            if (g < bm) n1 = par[bbase + g];
            asrc[cc] = H + (size_t)n1 * 1024 + HDIM + cs;
        }
        const f16* bsrc[3];
        int nbch[3];
#pragma unroll
        for (int cc = 0; cc < 3; ++cc) {
            int ch = w * 3 + cc;
            nbch[cc] = ch;
            bsrc[cc] = Wh + (size_t)(bx * 80 + ch * 8 + rch) * HDIM + cs;
        }

        f32x4 acc[2][5] = {};
#define STGB(sel, k0)                                                        \
        do {                                                                 \
            _Pragma("unroll")                                                \
            for (int cc = 0; cc < 4; ++cc)                                   \
                glds16(asrc[cc] + (k0),                                      \
                       Ab0 + (sel) * 8192 + (w * 4 + cc) * 512 + L * 8);     \
            _Pragma("unroll")                                                \
            for (int cc = 0; cc < 3; ++cc)                                   \
                if (nbch[cc] < 10)                                           \
                    glds16(bsrc[cc] + (k0),                                  \
                           Bb0 + (sel) * 5120 + nbch[cc] * 512 + L * 8);     \
        } while (0)

        STGB(0, 0);
        __syncthreads();
        int cur = 0;
        for (int tt = 0; tt < 8; ++tt) {
            if (tt + 1 < 8) STGB(cur ^ 1, (tt + 1) * 64);
            const f16* Ac = Ab0 + cur * 8192;
            const f16* Bc = Bb0 + cur * 5120;
            f16x8 af[2][2], bg[5][2];
#pragma unroll
            for (int i = 0; i < 2; ++i)
#pragma unroll
                for (int ks = 0; ks < 2; ++ks)
                    af[i][ks] = *(const f16x8*)(Ac + (wm + i * 16 + fr) * 64
                                + ((((ks * 4 + fq) << 3) ^ fsw)));
#pragma unroll
            for (int j = 0; j < 5; ++j)
#pragma unroll
                for (int ks = 0; ks < 2; ++ks)
                    bg[j][ks] = *(const f16x8*)(Bc + ((j) * 16 + fr) * 64
                                + ((((ks * 4 + fq) << 3) ^ fsw)));
#pragma unroll
            for (int ks = 0; ks < 2; ++ks)
#pragma unroll
                for (int i = 0; i < 2; ++i)
#pragma unroll
                    for (int j = 0; j < 5; ++j)
                        acc[i][j] = __builtin_amdgcn_mfma_f32_16x16x32_f16(
                            af[i][ks], bg[j][ks], acc[i][j], 0, 0, 0);
            __syncthreads();
            cur ^= 1;
        }
#undef STGB
#pragma unroll
        for (int i = 0; i < 2; ++i)
#pragma unroll
            for (int j = 0; j < 5; ++j)
#pragma unroll
                for (int rr = 0; rr < 4; ++rr)
                    Sg[(wm + i * 16 + fq * 4 + rr) * 84 + j * 16 + fr]
                        = acc[i][j][rr];
        __syncthreads();
        const int rmax = bm - by * 128;
        const int j0 = bx * 16;
        for (int cc = 0; cc < 8; ++cc) {
            int cell = t + cc * 256;
            int r = cell >> 4, j = cell & 15;
            if (r >= rmax) break;
            int node = bbase + by * 128 + r;
            int jj = j0 + j;
            const f16* pxr = PX + (size_t)node * NCAT;
            float g[5];
#pragma unroll
            for (int q = 0; q < 5; ++q)
                g[q] = (float)pxr[4096 + q * HDIM + jj] + bh[q * HDIM + jj]
                     + Sg[r * 84 + j * 5 + q];
            int p = par[node];
            float cp = cbb[(size_t)p * HDIM + jj];
            float i_ = sigm(g[0]), o_ = sigm(g[1]), f_ = sigm(g[2]);
            float u_ = tanhf(g[3]), r_ = sigm(g[4]);
            float c  = i_ * u_ + f_ * cp;
            float hc = o_ * tanhf(c);
            float px = (float)pxr[3584 + jj];
            float hf = r_ * hc + (1.0f - r_) * px;
            cbb[(size_t)node * HDIM + jj] = c;
            H[(size_t)node * 1024 + HDIM + jj] = (f16)hf;
            if (out32) out32[(size_t)node * 1024 + HDIM + jj] = hf;
        }
    }
}

// ---------------------------------------------------------------------------
// Elementwise for the no-GEMM cases only (fwd leaves + bwd root), vectorized.
// ---------------------------------------------------------------------------
__global__ __launch_bounds__(256) void elem_merged(
    const f16* __restrict__ PX,
    int fbase, int fm, int bbase, int bm,
    const int* __restrict__ lc, const int* __restrict__ rc,
    const int* __restrict__ par,
    float* __restrict__ cbf, float* __restrict__ cbb,
    f16* __restrict__ H, float* __restrict__ out32,
    const float* __restrict__ bl, const float* __restrict__ br,
    const float* __restrict__ bh)
{
    int t = blockIdx.x * 256 + threadIdx.x;
    const int fvec = fm * 64;               // HDIM/8 vectors per row
    if (t < fvec) {
        int row = t >> 6, j8 = (t & 63) << 3;
        int node = fbase + row;
        const f16* pxr = PX + (size_t)node * NCAT;
        float g[6][8];
#pragma unroll
        for (int q = 0; q < 6; ++q) {
            f16x8 pv = *(const f16x8*)(pxr + HDIM + q * HDIM + j8);
            const float* blp = bl + q * HDIM + j8;
            const float* brp = br + q * HDIM + j8;
#pragma unroll
            for (int e = 0; e < 8; ++e)
                g[q][e] = (float)pv[e] + blp[e] + brp[e];
        }
        int lcn = lc[node], rcn = rc[node];
        const float* clp = cbf + (size_t)lcn * HDIM + j8;
        const float* crp = cbf + (size_t)rcn * HDIM + j8;
        f32x4 cl0 = *(const f32x4*)clp, cl1 = *(const f32x4*)(clp + 4);
        f32x4 cr0 = *(const f32x4*)crp, cr1 = *(const f32x4*)(crp + 4);
        f16x8 pxv = *(const f16x8*)(pxr + j8);
        f32x4 co0, co1;
        f16x8 hv;
        f32x4 ho0, ho1;
#pragma unroll
        for (int e = 0; e < 8; ++e) {
            float clv = (e < 4) ? cl0[e & 3] : cl1[e & 3];
            float crv = (e < 4) ? cr0[e & 3] : cr1[e & 3];
            float i_ = sigm(g[0][e]), o_ = sigm(g[1][e]);
            float fl_ = sigm(g[2][e]), fr_ = sigm(g[3][e]);
            float u_ = tanhf(g[4][e]), r_ = sigm(g[5][e]);
            float c  = i_ * u_ + fl_ * clv + fr_ * crv;
            float hc = o_ * tanhf(c);
            float hf = r_ * hc + (1.0f - r_) * (float)pxv[e];
            if (e < 4) { co0[e & 3] = c; ho0[e & 3] = hf; }
            else       { co1[e & 3] = c; ho1[e & 3] = hf; }
            hv[e] = (f16)hf;
        }
        float* cdst = cbf + (size_t)node * HDIM + j8;
        *(f32x4*)cdst = co0; *(f32x4*)(cdst + 4) = co1;
        *(f16x8*)(H + (size_t)node * 1024 + j8) = hv;
        if (out32) {
            float* od = out32 + (size_t)node * 1024 + j8;
            *(f32x4*)od = ho0; *(f32x4*)(od + 4) = ho1;
        }
    } else {
        int t2 = t - fvec;
        if (t2 >= bm * 64) return;
        int row = t2 >> 6, j8 = (t2 & 63) << 3;
        int node = bbase + row;
        const f16* pxr = PX + (size_t)node * NCAT;
        float g[5][8];
#pragma unroll
        for (int q = 0; q < 5; ++q) {
            f16x8 pv = *(const f16x8*)(pxr + 4096 + q * HDIM + j8);
            const float* bhp = bh + q * HDIM + j8;
#pragma unroll
            for (int e = 0; e < 8; ++e)
                g[q][e] = (float)pv[e] + bhp[e];
        }
        int p = par[node];
        const float* cpp = cbb + (size_t)p * HDIM + j8;
        f32x4 cp0 = *(const f32x4*)cpp, cp1 = *(const f32x4*)(cpp + 4);
        f16x8 pxv = *(const f16x8*)(pxr + 3584 + j8);
        f32x4 co0, co1;
        f16x8 hv;
        f32x4 ho0, ho1;
#pragma unroll
        for (int e = 0; e < 8; ++e) {
            float cpv = (e < 4) ? cp0[e & 3] : cp1[e & 3];
            float i_ = sigm(g[0][e]), o_ = sigm(g[1][e]), f_ = sigm(g[2][e]);
            float u_ = tanhf(g[3][e]), r_ = sigm(g[4][e]);
            float c  = i_ * u_ + f_ * cpv;
            float hc = o_ * tanhf(c);
            float hf = r_ * hc + (1.0f - r_) * (float)pxv[e];
            if (e < 4) { co0[e & 3] = c; ho0[e & 3] = hf; }
            else       { co1[e & 3] = c; ho1[e & 3] = hf; }
            hv[e] = (f16)hf;
        }
        float* cdst = cbb + (size_t)node * HDIM + j8;
        *(f32x4*)cdst = co0; *(f32x4*)(cdst + 4) = co1;
        *(f16x8*)(H + (size_t)node * 1024 + HDIM + j8) = hv;
        if (out32) {
            float* od = out32 + (size_t)node * 1024 + HDIM + j8;
            *(f32x4*)od = ho0; *(f32x4*)(od + 4) = ho1;
        }
    }
}

extern "C" void kernel_launch(void* const* d_in, const int* in_sizes, int n_in,
                              void* d_out, int out_size, void* d_ws, size_t ws_size,
                              hipStream_t stream)
{
    (void)in_sizes; (void)n_in; (void)out_size; (void)ws_size;
    const float* features = (const float*)d_in[0];
    const float* fw_Wp = (const float*)d_in[1];
    const float* fw_bp = (const float*)d_in[2];
    const float* fw_Wx = (const float*)d_in[3];
    const float* fw_bx = (const float*)d_in[4];
    const float* fw_Wl = (const float*)d_in[5];
    const float* fw_bl = (const float*)d_in[6];
    const float* fw_Wr = (const float*)d_in[7];
    const float* fw_br = (const float*)d_in[8];
    const float* bw_Wp = (const float*)d_in[9];
    const float* bw_bp = (const float*)d_in[10];
    const float* bw_Wx = (const float*)d_in[11];
    const float* bw_bx = (const float*)d_in[12];
    const float* bw_Wh = (const float*)d_in[13];
    const float* bw_bh = (const float*)d_in[14];
    const int* lc  = (const int*)d_in[17];
    const int* rc  = (const int*)d_in[18];
    const int* par = (const int*)d_in[19];

    // workspace layout (f16 units unless noted), ~113 MB.
    f16* feat16 = (f16*)d_ws;                       // 4096*1024
    f16* H      = feat16 + (size_t)4096 * 1024;     // 4097*1024
    f16* Wcat   = H     + (size_t)4097 * 1024;      // 6656*1024
    f16* Wlr    = Wcat  + (size_t)NCAT * 1024;      // 3072*1024 (gate-interleaved)
    f16* Wh     = Wlr   + (size_t)3072 * 1024;      // 2560*512  (gate-interleaved)
    f16* PX     = Wh    + (size_t)2560 * 512;       // 4096*6656
    float* biascat = (float*)(PX + (size_t)4096 * NCAT);
    float* cbf     = biascat + NCAT;                // 4097*512 f32
    float* cbb     = cbf + (size_t)4097 * HDIM;     // 4097*512 f32

    zero_slots<<<dim3(1), dim3(1024), 0, stream>>>(H, cbf, cbb);
    cvt16<<<dim3(2048), 256, 0, stream>>>(features, feat16, 4096 * 1024 / 8);

    // stage schedule (per layer): merged launch i pairs fwd stage i with bwd
    // stage i. fwd: special node 2047, then levels 10..0. bwd: levels 1..12.
    static const int fb[12] = {2047, 1023, 511, 255, 127, 63, 31, 15, 7, 3, 1, 0};
    static const int fmv[12] = {1, 1024, 512, 256, 128, 64, 32, 16, 8, 4, 2, 1};
    static const int bb[12] = {1, 3, 7, 15, 31, 63, 127, 255, 511, 1023, 2047, 4095};
    static const int bmv[12] = {2, 4, 8, 16, 32, 64, 128, 256, 512, 1024, 2048, 1};

    for (int l = 0; l < 2; ++l) {
        prep_layer<<<dim3(5530), 256, 0, stream>>>(
            fw_Wp + (size_t)l * 512 * 1024,  fw_Wx + (size_t)l * 3072 * 1024,
            bw_Wp + (size_t)l * 512 * 1024,  bw_Wx + (size_t)l * 2560 * 1024,
            fw_Wl + (size_t)l * 3072 * 512,  fw_Wr + (size_t)l * 3072 * 512,
            bw_Wh + (size_t)l * 2560 * 512,
            fw_bp + (size_t)l * 512, fw_bx + (size_t)l * 3072,
            bw_bp + (size_t)l * 512, bw_bx + (size_t)l * 2560,
            Wcat, Wlr, Wh, biascat);

        // fused precompute: PX[4096][6656] = A @ [Wp_f|Wx_f|Wp_b|Wx_b]^T + bias
        const f16* A16 = (l == 0) ? feat16 : H;
        mm_pre8<<<dim3(NCAT / 256, 4096 / 256), 512, 0, stream>>>(
            A16, Wcat, biascat, PX, NCAT, 1024);

        float* o32 = (l == 1) ? (float*)d_out : nullptr;
        const float* bl_l = fw_bl + (size_t)l * 3072;
        const float* br_l = fw_br + (size_t)l * 3072;
        const float* bh_l = bw_bh + (size_t)l * 2560;

        // merged leaves (fwd, m=2048) + root (bwd, m=1): no GEMM needed
        {
            int tot = (2048 + 1) * 64;
            elem_merged<<<dim3((tot + 255) / 256), 256, 0, stream>>>(
                PX, 2048, 2048, 0, 1,
                lc, rc, par, cbf, cbb, H, o32, bl_l, br_l, bh_l);
        }
        for (int i = 0; i < 12; ++i) {
            int nfB = ((fmv[i] + 127) >> 7) * 32;
            int nbB = ((bmv[i] + 127) >> 7) * 32;
            stage_fused<<<dim3(nfB + nbB), 256, 0, stream>>>(
                Wlr, Wh, H, PX, lc, rc, par,
                fb[i], fmv[i], bb[i], bmv[i],
                cbf, cbb, o32, bl_l, br_l, bh_l);
        }
    }
    // layer-1 stage/elem kernels wrote d_out directly; nothing else to copy
}

// Round 7
// 751.663 us; speedup vs baseline: 1.0343x; 1.0343x over previous
//
#include <hip/hip_runtime.h>
#include <cstdint>
#include <cstddef>

// ---------------------------------------------------------------------------
// MultiLayer bidirectional TreeLSTM, N=4096 heap tree, H=512, L=2.
// R13: stage_fused K-loops rebuilt as ring-4 deep pipeline (T3+T4): 4 LDS
// buffers, 2-tile prefetch depth, reads-before-barrier (m201 placement),
// counted per-wave vmcnt (fwd 7; bwd w0-2:7, w3:5 via wave-uniform branch),
// one s_barrier per K-step, no __syncthreads in the loop. Ring-4 is the
// minimum race-free depth: buf X (read at iter t) is rewritten only by waves
// past BAR(t+1), and reaching BAR(t+1) implies MFMA(t) issued, i.e. X's
// ds_reads drained by lgkmcnt. LDS 112 KB -> 1 blk/CU (stages are latency-
// not occupancy-bound). mm_pre8/prep/elem identical to R12 (777 us).
// ---------------------------------------------------------------------------

#define HDIM 512
#define ZROW 4096
#define NCAT 6656   // 512 px_f | 3072 x2_f | 512 px_b | 2560 x2_b

typedef _Float16 f16;
typedef f16   f16x8 __attribute__((ext_vector_type(8)));
typedef float f32x4 __attribute__((ext_vector_type(4)));

__device__ __forceinline__ float sigm(float x) { return 1.0f / (1.0f + expf(-x)); }

// direct global->LDS DMA, 16 B per lane; LDS dest linear (base + lane*16).
__device__ __forceinline__ void glds16(const f16* g, f16* l)
{
    __builtin_amdgcn_global_load_lds(
        (const __attribute__((address_space(1))) void*)g,
        (__attribute__((address_space(3))) void*)l,
        16, 0, 0);
}

#define VM7()   asm volatile("s_waitcnt vmcnt(7)" ::: "memory")
#define VM5()   asm volatile("s_waitcnt vmcnt(5)" ::: "memory")
#define VM4()   asm volatile("s_waitcnt vmcnt(4)" ::: "memory")
#define VM0()   asm volatile("s_waitcnt vmcnt(0)" ::: "memory")
#define BAR()   do { __builtin_amdgcn_s_barrier(); \
                     __builtin_amdgcn_sched_barrier(0); } while (0)
#define SP1()   __builtin_amdgcn_s_setprio(1)
#define SP0()   __builtin_amdgcn_s_setprio(0)

__device__ __forceinline__ void cvt8s(const float* __restrict__ s, f16* __restrict__ d)
{
    float4 v0 = ((const float4*)s)[0];
    float4 v1 = ((const float4*)s)[1];
    f16x8 o;
    o[0] = (f16)v0.x; o[1] = (f16)v0.y; o[2] = (f16)v0.z; o[3] = (f16)v0.w;
    o[4] = (f16)v1.x; o[5] = (f16)v1.y; o[6] = (f16)v1.z; o[7] = (f16)v1.w;
    *(f16x8*)d = o;
}

__global__ __launch_bounds__(256) void cvt16(
    const float* __restrict__ s, f16* __restrict__ d, int n8)
{
    int i = blockIdx.x * 256 + threadIdx.x;
    if (i >= n8) return;
    cvt8s(s + (size_t)i * 8, d + (size_t)i * 8);
}

// ---------------------------------------------------------------------------
// One-launch per-layer weight prep (R10-proven).
// ---------------------------------------------------------------------------
__global__ __launch_bounds__(256) void prep_layer(
    const float* __restrict__ fWp, const float* __restrict__ fWx,
    const float* __restrict__ bWp, const float* __restrict__ bWx,
    const float* __restrict__ fWl, const float* __restrict__ fWr,
    const float* __restrict__ bWh,
    const float* __restrict__ fbp, const float* __restrict__ fbx,
    const float* __restrict__ bbp, const float* __restrict__ bbx,
    f16* __restrict__ Wcat, f16* __restrict__ Wlr, f16* __restrict__ Wh,
    float* __restrict__ biascat)
{
    const int bid = blockIdx.x;
    const int t   = threadIdx.x;
    if (bid < 256) {
        int i = bid * 256 + t;
        cvt8s(fWp + (size_t)i * 8, Wcat + (size_t)i * 8);
    } else if (bid < 1792) {
        int i = (bid - 256) * 256 + t;
        cvt8s(fWx + (size_t)i * 8, Wcat + (size_t)512 * 1024 + (size_t)i * 8);
    } else if (bid < 2048) {
        int i = (bid - 1792) * 256 + t;
        cvt8s(bWp + (size_t)i * 8, Wcat + (size_t)3584 * 1024 + (size_t)i * 8);
    } else if (bid < 3328) {
        int i = (bid - 2048) * 256 + t;
        cvt8s(bWx + (size_t)i * 8, Wcat + (size_t)4096 * 1024 + (size_t)i * 8);
    } else if (bid < 4864) {
        int i = (bid - 3328) * 256 + t;        // over 3072*1024/8
        int col8 = (i * 8) & 1023;
        int row  = (i * 8) >> 10;
        const float* s = (col8 < HDIM) ? (fWl + (size_t)row * HDIM + col8)
                                       : (fWr + (size_t)row * HDIM + col8 - HDIM);
        int np = (row & 511) * 6 + (row >> 9);
        cvt8s(s, Wlr + (size_t)np * 1024 + col8);
    } else if (bid < 5504) {
        int i = (bid - 4864) * 256 + t;        // over 2560*512/8
        int col8 = (i * 8) & 511;
        int row  = (i * 8) >> 9;
        int np = (row & 511) * 5 + (row >> 9);
        cvt8s(bWh + (size_t)row * HDIM + col8, Wh + (size_t)np * HDIM + col8);
    } else {
        int i = (bid - 5504) * 256 + t;
        if (i >= NCAT) return;
        float v;
        if (i < 512) v = fbp[i];
        else if (i < 3584) v = fbx[i - 512];
        else if (i < 4096) v = bbp[i - 3584];
        else v = bbx[i - 4096];
        biascat[i] = v;
    }
}

__global__ void zero_slots(f16* H, float* cbf, float* cbb)
{
    int t = threadIdx.x;  // 1024 threads
    H[(size_t)ZROW * 1024 + t] = (f16)0.0f;
    if (t < HDIM) {
        cbf[(size_t)ZROW * HDIM + t] = 0.0f;
        cbb[(size_t)ZROW * HDIM + t] = 0.0f;
    }
}

// ---------------------------------------------------------------------------
// Precompute GEMM, 256^2 phase-pipelined (R12-proven, 70.5 us @ 792 TF).
// ---------------------------------------------------------------------------
__global__ __launch_bounds__(512) void mm_pre8(
    const f16* __restrict__ A, const f16* __restrict__ W,
    const float* __restrict__ bias, f16* __restrict__ C, int N, int K)
{
    __shared__ __align__(16) f16 lds[2][2][16384];   // [buf][A=0/B=1], 128 KiB
    const int t   = threadIdx.x;
    const int L   = t & 63;
    const int wid = t >> 6;
    const int wr  = wid >> 2;        // 0..1  (M)
    const int wc  = wid & 3;         // 0..3  (N)
    const int fr  = L & 15;
    const int fq  = L >> 4;
    // staging geometry
    const int srow = t >> 3;                          // 0..63
    const int cs   = (((t & 7) ^ (srow & 7)) << 3);   // swizzled global col (f16)
    const int vrow = ((srow >> 5) << 6) + (srow & 31);
    const int bB0  = (srow >= 32) ? 2048 : 0;
    const f16* Ag = A + (size_t)(blockIdx.y * 256) * K + cs;
    const f16* Bg = W + (size_t)(blockIdx.x * 256) * K + cs;
    // frag-read swizzled col offsets (f16 units), ks = 0/1
    const int xa0 = ((fq)     ^ (fr & 7)) << 3;
    const int xa1 = ((4 + fq) ^ (fr & 7)) << 3;

#define STG_A(nb, T, u)                                                      \
    do {                                                                     \
        glds16(Ag + (size_t)(srow + (u) * 64) * K + (T) * 64,                \
               &lds[nb][0][(u) * 4096 + t * 8]);                             \
        glds16(Ag + (size_t)(srow + (u) * 64 + 128) * K + (T) * 64,          \
               &lds[nb][0][(u) * 4096 + 8192 + t * 8]);                      \
    } while (0)
#define STG_B(nb, T, v)                                                      \
    do {                                                                     \
        glds16(Bg + (size_t)(vrow + (v) * 32) * K + (T) * 64,                \
               &lds[nb][1][(v) * 2048 + bB0 + t * 8]);                       \
        glds16(Bg + (size_t)(vrow + (v) * 32 + 128) * K + (T) * 64,          \
               &lds[nb][1][(v) * 2048 + bB0 + 8192 + t * 8]);                \
    } while (0)

    f32x4 acc[8][4] = {};
    f16x8 a0f[4][2], a1f[4][2], b0f[2][2], b1f[2][2];

#define LDA(AF, Ar, mh)                                                            \
    do {                                                                           \
        _Pragma("unroll") for (int i2 = 0; i2 < 4; ++i2) {                         \
            AF[i2][0] = *(const f16x8*)((Ar) + ((mh) * 64 + i2 * 16) * 64 + xa0);  \
            AF[i2][1] = *(const f16x8*)((Ar) + ((mh) * 64 + i2 * 16) * 64 + xa1);  \
        }                                                                          \
    } while (0)
#define LDB(BF, Br, nh)                                                            \
    do {                                                                           \
        _Pragma("unroll") for (int j2 = 0; j2 < 2; ++j2) {                         \
            BF[j2][0] = *(const f16x8*)((Br) + ((nh) * 32 + j2 * 16) * 64 + xa0);  \
            BF[j2][1] = *(const f16x8*)((Br) + ((nh) * 32 + j2 * 16) * 64 + xa1);  \
        }                                                                          \
    } while (0)
#define MF(AF, BF, mh, nh)                                                         \
    do {                                                                           \
        _Pragma("unroll") for (int ks = 0; ks < 2; ++ks)                           \
        _Pragma("unroll") for (int i2 = 0; i2 < 4; ++i2)                           \
        _Pragma("unroll") for (int j2 = 0; j2 < 2; ++j2)                           \
            acc[(mh) * 4 + i2][(nh) * 2 + j2] =                                    \
                __builtin_amdgcn_mfma_f32_16x16x32_f16(                            \
                    AF[i2][ks], BF[j2][ks],                                        \
                    acc[(mh) * 4 + i2][(nh) * 2 + j2], 0, 0, 0);                   \
    } while (0)

    const int NT = K >> 6;
    // prologue: stage tile 0 fully, drain, barrier.
    STG_A(0, 0, 0); STG_B(0, 0, 0); STG_B(0, 0, 1); STG_A(0, 0, 1);
    VM0();
    BAR();

    for (int T = 0; T < NT; ++T) {
        const int cb = T & 1, nb = cb ^ 1;
        const bool pf = (T + 1 < NT);
        const f16* Ar = &lds[cb][0][(wr * 128 + fr) * 64];
        const f16* Br = &lds[cb][1][(wc * 64 + fr) * 64];
        // ---- P0: quadrant (0,0); reads A0,B0; stage U0(T+1) ----
        LDA(a0f, Ar, 0); LDB(b0f, Br, 0);
        if (pf) STG_A(nb, T + 1, 0);
        VM4(); BAR();
        SP1(); MF(a0f, b0f, 0, 0); SP0();
        // ---- P1: quadrant (0,1); reads B1; stage V0(T+1) ----
        LDB(b1f, Br, 1);
        if (pf) STG_B(nb, T + 1, 0);
        VM4(); BAR();
        SP1(); MF(a0f, b1f, 0, 1); SP0();
        // ---- P2: quadrant (1,1); reads A1; stage V1(T+1) ----
        LDA(a1f, Ar, 1);
        if (pf) STG_B(nb, T + 1, 1);
        VM4(); BAR();
        SP1(); MF(a1f, b1f, 1, 1); SP0();
        // ---- P3: quadrant (1,0); no reads; stage U1(T+1) ----
        if (pf) STG_A(nb, T + 1, 1);
        VM4(); BAR();
        SP1(); MF(a1f, b0f, 1, 0); SP0();
    }
#undef STG_A
#undef STG_B
#undef LDA
#undef LDB
#undef MF

    // C/D layout: col = lane&15, row = (lane>>4)*4 + reg  [m89-verified]
    const int gr0 = blockIdx.y * 256 + wr * 128 + fq * 4;
    const int gc0 = blockIdx.x * 256 + wc * 64 + fr;
#pragma unroll
    for (int j = 0; j < 4; ++j) {
        const int gc = gc0 + j * 16;
        const float bj = bias[gc];
#pragma unroll
        for (int i = 0; i < 8; ++i) {
            const int gr = gr0 + i * 16;
#pragma unroll
            for (int rr = 0; rr < 4; ++rr)
                C[(size_t)(gr + rr) * N + gc] = (f16)(acc[i][j][rr] + bj);
        }
    }
}

// ---------------------------------------------------------------------------
// Fused stage kernel: GEMM (gathered A rows) + LSTM cell math + H/c writes.
// R13: ring-4 LDS (Ab 4x8192 f16, Bb 4x6144/5120 f16, 112 KB), 2-tile-deep
// glds prefetch, reads-before-barrier, counted vmcnt (fwd 7 all waves; bwd
// 7 for w0-2 / 5 for w3 — wave-uniform branch), one s_barrier per K-step.
//   fwd blocks: 128 rows x 96 cols (j-span 16, all 6 gates), K=1024, 16 it
//   bwd blocks: 128 rows x 80 cols (j-span 16, all 5 gates), K=512,   8 it
// ---------------------------------------------------------------------------
__global__ __launch_bounds__(256) void stage_fused(
    const f16* __restrict__ Wlr, const f16* __restrict__ Wh,
    f16* H, const f16* __restrict__ PX,
    const int* __restrict__ lc, const int* __restrict__ rc,
    const int* __restrict__ par,
    int fbase, int fm, int bbase, int bm,
    float* __restrict__ cbf, float* __restrict__ cbb,
    float* out32,
    const float* __restrict__ bl, const float* __restrict__ br,
    const float* __restrict__ bh)
{
    __shared__ __align__(16) char smem[114688];
    f16*   Ab0 = (f16*)smem;             // ring-4 A: buf b at b*8192 f16 (64 KB)
    f16*   Bb0 = (f16*)(smem + 65536);   // ring-4 B: buf b at b*6144 (fwd) / 5120 (bwd)
    float* Sg  = (float*)smem;           // epilogue scoreboard (aliases staging)

    const int t   = threadIdx.x;
    const int L   = t & 63;
    const int w   = t >> 6;
    const int fr  = L & 15;
    const int fq  = L >> 4;
    const int rch = L >> 3;                       // row within 8-row chunk
    const int cs  = (((L & 7) ^ rch) << 3);       // swizzled source col (f16, <64)
    const int fsw = (fr & 7) << 3;                // frag-read swizzle (f16 units)
    const int nfB = ((fm + 127) >> 7) * 32;

    if ((int)blockIdx.x < nfB) {
        // ----------------- forward (leaves-to-root) tile -----------------
        const int by = blockIdx.x >> 5;
        const int bx = blockIdx.x & 31;
        const int wm = (w & 1) << 6;
        const int wn = (w >> 1) * 48;

        const f16* aLo[4]; const f16* aHi[4];
#pragma unroll
        for (int cc = 0; cc < 4; ++cc) {
            int g  = by * 128 + (w * 4 + cc) * 8 + rch;
            int n1 = ZROW, n2 = ZROW;
            if (g < fm) { n1 = lc[fbase + g]; n2 = rc[fbase + g]; }
            aLo[cc] = H + (size_t)n1 * 1024 + cs;
            aHi[cc] = H + (size_t)n2 * 1024 + cs - HDIM;
        }
        const f16* bsrc[3];
#pragma unroll
        for (int cc = 0; cc < 3; ++cc)
            bsrc[cc] = Wlr + (size_t)(bx * 96 + (w * 3 + cc) * 8 + rch) * 1024 + cs;

        f32x4 acc[4][3] = {};
#define STGF(b, k0)                                                          \
        do {                                                                 \
            const bool hiK = (k0) >= HDIM;                                   \
            _Pragma("unroll")                                                \
            for (int cc = 0; cc < 4; ++cc)                                   \
                glds16((hiK ? aHi[cc] : aLo[cc]) + (k0),                     \
                       Ab0 + (b) * 8192 + (w * 4 + cc) * 512 + L * 8);       \
            _Pragma("unroll")                                                \
            for (int cc = 0; cc < 3; ++cc)                                   \
                glds16(bsrc[cc] + (k0),                                      \
                       Bb0 + (b) * 6144 + (w * 3 + cc) * 512 + L * 8);       \
        } while (0)

        STGF(0, 0); STGF(1, 64);
        VM7(); BAR();
        for (int tt = 0; tt < 16; ++tt) {
            const f16* Ac = Ab0 + (tt & 3) * 8192;
            const f16* Bc = Bb0 + (tt & 3) * 6144;
            f16x8 af[4][2], bg[3][2];
#pragma unroll
            for (int i = 0; i < 4; ++i)
#pragma unroll
                for (int ks = 0; ks < 2; ++ks)
                    af[i][ks] = *(const f16x8*)(Ac + (wm + i * 16 + fr) * 64
                                + ((((ks * 4 + fq) << 3) ^ fsw)));
#pragma unroll
            for (int j = 0; j < 3; ++j)
#pragma unroll
                for (int ks = 0; ks < 2; ++ks)
                    bg[j][ks] = *(const f16x8*)(Bc + (wn + j * 16 + fr) * 64
                                + ((((ks * 4 + fq) << 3) ^ fsw)));
            if (tt + 2 < 16) { STGF((tt + 2) & 3, (tt + 2) * 64); VM7(); }
            else if (tt + 1 < 16) VM0();
            BAR();
#pragma unroll
            for (int ks = 0; ks < 2; ++ks)
#pragma unroll
                for (int i = 0; i < 4; ++i)
#pragma unroll
                    for (int j = 0; j < 3; ++j)
                        acc[i][j] = __builtin_amdgcn_mfma_f32_16x16x32_f16(
                            af[i][ks], bg[j][ks], acc[i][j], 0, 0, 0);
        }
#undef STGF
        __syncthreads();
        // epilogue: acc -> Sg[128][100]
#pragma unroll
        for (int i = 0; i < 4; ++i)
#pragma unroll
            for (int j = 0; j < 3; ++j)
#pragma unroll
                for (int rr = 0; rr < 4; ++rr)
                    Sg[(wm + i * 16 + fq * 4 + rr) * 100 + wn + j * 16 + fr]
                        = acc[i][j][rr];
        __syncthreads();
        const int rmax = fm - by * 128;
        const int j0 = bx * 16;
        for (int cc = 0; cc < 8; ++cc) {
            int cell = t + cc * 256;
            int r = cell >> 4, j = cell & 15;
            if (r >= rmax) break;                 // r strictly increases with cc
            int node = fbase + by * 128 + r;
            int jj = j0 + j;
            const f16* pxr = PX + (size_t)node * NCAT;
            float g[6];
#pragma unroll
            for (int q = 0; q < 6; ++q)
                g[q] = (float)pxr[HDIM + q * HDIM + jj] + bl[q * HDIM + jj]
                     + br[q * HDIM + jj] + Sg[r * 100 + j * 6 + q];
            int lcn = lc[node], rcn = rc[node];
            float clv = cbf[(size_t)lcn * HDIM + jj];
            float crv = cbf[(size_t)rcn * HDIM + jj];
            float i_ = sigm(g[0]), o_ = sigm(g[1]), fl_ = sigm(g[2]), fr_ = sigm(g[3]);
            float u_ = tanhf(g[4]), r_ = sigm(g[5]);
            float c  = i_ * u_ + fl_ * clv + fr_ * crv;
            float hc = o_ * tanhf(c);
            float px = (float)pxr[jj];
            float hf = r_ * hc + (1.0f - r_) * px;
            cbf[(size_t)node * HDIM + jj] = c;
            H[(size_t)node * 1024 + jj] = (f16)hf;
            if (out32) out32[(size_t)node * 1024 + jj] = hf;
        }
    } else {
        // ----------------- backward (root-to-leaves) tile ----------------
        const int b2 = blockIdx.x - nfB;
        const int by = b2 >> 5;
        const int bx = b2 & 31;
        const int wm = w * 32;                    // 4 waves x 32 rows

        const f16* asrc[4];
#pragma unroll
        for (int cc = 0; cc < 4; ++cc) {
            int g = by * 128 + (w * 4 + cc) * 8 + rch;
            int n1 = ZROW;
            if (g < bm) n1 = par[bbase + g];
            asrc[cc] = H + (size_t)n1 * 1024 + HDIM + cs;
        }
        const f16* bsrc[3];
        int nbch[3];
#pragma unroll
        for (int cc = 0; cc < 3; ++cc) {
            int ch = w * 3 + cc;
            nbch[cc] = ch;
            bsrc[cc] = Wh + (size_t)(bx * 80 + ch * 8 + rch) * HDIM + cs;
        }

        f32x4 acc[2][5] = {};
#define STGB(b, k0)                                                          \
        do {                                                                 \
            _Pragma("unroll")                                                \
            for (int cc = 0; cc < 4; ++cc)                                   \
                glds16(asrc[cc] + (k0),                                      \
                       Ab0 + (b) * 8192 + (w * 4 + cc) * 512 + L * 8);       \
            _Pragma("unroll")                                                \
            for (int cc = 0; cc < 3; ++cc)                                   \
                if (nbch[cc] < 10)                                           \
                    glds16(bsrc[cc] + (k0),                                  \
                           Bb0 + (b) * 5120 + nbch[cc] * 512 + L * 8);       \
        } while (0)
#define VMB()   do { if (w == 3) { VM5(); } else { VM7(); } } while (0)

        STGB(0, 0); STGB(1, 64);
        VMB(); BAR();
        for (int tt = 0; tt < 8; ++tt) {
            const f16* Ac = Ab0 + (tt & 3) * 8192;
            const f16* Bc = Bb0 + (tt & 3) * 5120;
            f16x8 af[2][2], bg[5][2];
#pragma unroll
            for (int i = 0; i < 2; ++i)
#pragma unroll
                for (int ks = 0; ks < 2; ++ks)
                    af[i][ks] = *(const f16x8*)(Ac + (wm + i * 16 + fr) * 64
                                + ((((ks * 4 + fq) << 3) ^ fsw)));
#pragma unroll
            for (int j = 0; j < 5; ++j)
#pragma unroll
                for (int ks = 0; ks < 2; ++ks)
                    bg[j][ks] = *(const f16x8*)(Bc + ((j) * 16 + fr) * 64
                                + ((((ks * 4 + fq) << 3) ^ fsw)));
            if (tt + 2 < 8) { STGB((tt + 2) & 3, (tt + 2) * 64); VMB(); }
            else if (tt + 1 < 8) VM0();
            BAR();
#pragma unroll
            for (int ks = 0; ks < 2; ++ks)
#pragma unroll
                for (int i = 0; i < 2; ++i)
#pragma unroll
                    for (int j = 0; j < 5; ++j)
                        acc[i][j] = __builtin_amdgcn_mfma_f32_16x16x32_f16(
                            af[i][ks], bg[j][ks], acc[i][j], 0, 0, 0);
        }
#undef STGB
#undef VMB
        __syncthreads();
#pragma unroll
        for (int i = 0; i < 2; ++i)
#pragma unroll
            for (int j = 0; j < 5; ++j)
#pragma unroll
                for (int rr = 0; rr < 4; ++rr)
                    Sg[(wm + i * 16 + fq * 4 + rr) * 84 + j * 16 + fr]
                        = acc[i][j][rr];
        __syncthreads();
        const int rmax = bm - by * 128;
        const int j0 = bx * 16;
        for (int cc = 0; cc < 8; ++cc) {
            int cell = t + cc * 256;
            int r = cell >> 4, j = cell & 15;
            if (r >= rmax) break;
            int node = bbase + by * 128 + r;
            int jj = j0 + j;
            const f16* pxr = PX + (size_t)node * NCAT;
            float g[5];
#pragma unroll
            for (int q = 0; q < 5; ++q)
                g[q] = (float)pxr[4096 + q * HDIM + jj] + bh[q * HDIM + jj]
                     + Sg[r * 84 + j * 5 + q];
            int p = par[node];
            float cp = cbb[(size_t)p * HDIM + jj];
            float i_ = sigm(g[0]), o_ = sigm(g[1]), f_ = sigm(g[2]);
            float u_ = tanhf(g[3]), r_ = sigm(g[4]);
            float c  = i_ * u_ + f_ * cp;
            float hc = o_ * tanhf(c);
            float px = (float)pxr[3584 + jj];
            float hf = r_ * hc + (1.0f - r_) * px;
            cbb[(size_t)node * HDIM + jj] = c;
            H[(size_t)node * 1024 + HDIM + jj] = (f16)hf;
            if (out32) out32[(size_t)node * 1024 + HDIM + jj] = hf;
        }
    }
}

// ---------------------------------------------------------------------------
// Elementwise for the no-GEMM cases only (fwd leaves + bwd root), vectorized.
// ---------------------------------------------------------------------------
__global__ __launch_bounds__(256) void elem_merged(
    const f16* __restrict__ PX,
    int fbase, int fm, int bbase, int bm,
    const int* __restrict__ lc, const int* __restrict__ rc,
    const int* __restrict__ par,
    float* __restrict__ cbf, float* __restrict__ cbb,
    f16* __restrict__ H, float* __restrict__ out32,
    const float* __restrict__ bl, const float* __restrict__ br,
    const float* __restrict__ bh)
{
    int t = blockIdx.x * 256 + threadIdx.x;
    const int fvec = fm * 64;               // HDIM/8 vectors per row
    if (t < fvec) {
        int row = t >> 6, j8 = (t & 63) << 3;
        int node = fbase + row;
        const f16* pxr = PX + (size_t)node * NCAT;
        float g[6][8];
#pragma unroll
        for (int q = 0; q < 6; ++q) {
            f16x8 pv = *(const f16x8*)(pxr + HDIM + q * HDIM + j8);
            const float* blp = bl + q * HDIM + j8;
            const float* brp = br + q * HDIM + j8;
#pragma unroll
            for (int e = 0; e < 8; ++e)
                g[q][e] = (float)pv[e] + blp[e] + brp[e];
        }
        int lcn = lc[node], rcn = rc[node];
        const float* clp = cbf + (size_t)lcn * HDIM + j8;
        const float* crp = cbf + (size_t)rcn * HDIM + j8;
        f32x4 cl0 = *(const f32x4*)clp, cl1 = *(const f32x4*)(clp + 4);
        f32x4 cr0 = *(const f32x4*)crp, cr1 = *(const f32x4*)(crp + 4);
        f16x8 pxv = *(const f16x8*)(pxr + j8);
        f32x4 co0, co1;
        f16x8 hv;
        f32x4 ho0, ho1;
#pragma unroll
        for (int e = 0; e < 8; ++e) {
            float clv = (e < 4) ? cl0[e & 3] : cl1[e & 3];
            float crv = (e < 4) ? cr0[e & 3] : cr1[e & 3];
            float i_ = sigm(g[0][e]), o_ = sigm(g[1][e]);
            float fl_ = sigm(g[2][e]), fr_ = sigm(g[3][e]);
            float u_ = tanhf(g[4][e]), r_ = sigm(g[5][e]);
            float c  = i_ * u_ + fl_ * clv + fr_ * crv;
            float hc = o_ * tanhf(c);
            float hf = r_ * hc + (1.0f - r_) * (float)pxv[e];
            if (e < 4) { co0[e & 3] = c; ho0[e & 3] = hf; }
            else       { co1[e & 3] = c; ho1[e & 3] = hf; }
            hv[e] = (f16)hf;
        }
        float* cdst = cbf + (size_t)node * HDIM + j8;
        *(f32x4*)cdst = co0; *(f32x4*)(cdst + 4) = co1;
        *(f16x8*)(H + (size_t)node * 1024 + j8) = hv;
        if (out32) {
            float* od = out32 + (size_t)node * 1024 + j8;
            *(f32x4*)od = ho0; *(f32x4*)(od + 4) = ho1;
        }
    } else {
        int t2 = t - fvec;
        if (t2 >= bm * 64) return;
        int row = t2 >> 6, j8 = (t2 & 63) << 3;
        int node = bbase + row;
        const f16* pxr = PX + (size_t)node * NCAT;
        float g[5][8];
#pragma unroll
        for (int q = 0; q < 5; ++q) {
            f16x8 pv = *(const f16x8*)(pxr + 4096 + q * HDIM + j8);
            const float* bhp = bh + q * HDIM + j8;
#pragma unroll
            for (int e = 0; e < 8; ++e)
                g[q][e] = (float)pv[e] + bhp[e];
        }
        int p = par[node];
        const float* cpp = cbb + (size_t)p * HDIM + j8;
        f32x4 cp0 = *(const f32x4*)cpp, cp1 = *(const f32x4*)(cpp + 4);
        f16x8 pxv = *(const f16x8*)(pxr + 3584 + j8);
        f32x4 co0, co1;
        f16x8 hv;
        f32x4 ho0, ho1;
#pragma unroll
        for (int e = 0; e < 8; ++e) {
            float cpv = (e < 4) ? cp0[e & 3] : cp1[e & 3];
            float i_ = sigm(g[0][e]), o_ = sigm(g[1][e]), f_ = sigm(g[2][e]);
            float u_ = tanhf(g[3][e]), r_ = sigm(g[4][e]);
            float c  = i_ * u_ + f_ * cpv;
            float hc = o_ * tanhf(c);
            float hf = r_ * hc + (1.0f - r_) * (float)pxv[e];
            if (e < 4) { co0[e & 3] = c; ho0[e & 3] = hf; }
            else       { co1[e & 3] = c; ho1[e & 3] = hf; }
            hv[e] = (f16)hf;
        }
        float* cdst = cbb + (size_t)node * HDIM + j8;
        *(f32x4*)cdst = co0; *(f32x4*)(cdst + 4) = co1;
        *(f16x8*)(H + (size_t)node * 1024 + HDIM + j8) = hv;
        if (out32) {
            float* od = out32 + (size_t)node * 1024 + HDIM + j8;
            *(f32x4*)od = ho0; *(f32x4*)(od + 4) = ho1;
        }
    }
}

extern "C" void kernel_launch(void* const* d_in, const int* in_sizes, int n_in,
                              void* d_out, int out_size, void* d_ws, size_t ws_size,
                              hipStream_t stream)
{
    (void)in_sizes; (void)n_in; (void)out_size; (void)ws_size;
    const float* features = (const float*)d_in[0];
    const float* fw_Wp = (const float*)d_in[1];
    const float* fw_bp = (const float*)d_in[2];
    const float* fw_Wx = (const float*)d_in[3];
    const float* fw_bx = (const float*)d_in[4];
    const float* fw_Wl = (const float*)d_in[5];
    const float* fw_bl = (const float*)d_in[6];
    const float* fw_Wr = (const float*)d_in[7];
    const float* fw_br = (const float*)d_in[8];
    const float* bw_Wp = (const float*)d_in[9];
    const float* bw_bp = (const float*)d_in[10];
    const float* bw_Wx = (const float*)d_in[11];
    const float* bw_bx = (const float*)d_in[12];
    const float* bw_Wh = (const float*)d_in[13];
    const float* bw_bh = (const float*)d_in[14];
    const int* lc  = (const int*)d_in[17];
    const int* rc  = (const int*)d_in[18];
    const int* par = (const int*)d_in[19];

    // workspace layout (f16 units unless noted), ~113 MB.
    f16* feat16 = (f16*)d_ws;                       // 4096*1024
    f16* H      = feat16 + (size_t)4096 * 1024;     // 4097*1024
    f16* Wcat   = H     + (size_t)4097 * 1024;      // 6656*1024
    f16* Wlr    = Wcat  + (size_t)NCAT * 1024;      // 3072*1024 (gate-interleaved)
    f16* Wh     = Wlr   + (size_t)3072 * 1024;      // 2560*512  (gate-interleaved)
    f16* PX     = Wh    + (size_t)2560 * 512;       // 4096*6656
    float* biascat = (float*)(PX + (size_t)4096 * NCAT);
    float* cbf     = biascat + NCAT;                // 4097*512 f32
    float* cbb     = cbf + (size_t)4097 * HDIM;     // 4097*512 f32

    zero_slots<<<dim3(1), dim3(1024), 0, stream>>>(H, cbf, cbb);
    cvt16<<<dim3(2048), 256, 0, stream>>>(features, feat16, 4096 * 1024 / 8);

    // stage schedule (per layer): merged launch i pairs fwd stage i with bwd
    // stage i. fwd: special node 2047, then levels 10..0. bwd: levels 1..12.
    static const int fb[12] = {2047, 1023, 511, 255, 127, 63, 31, 15, 7, 3, 1, 0};
    static const int fmv[12] = {1, 1024, 512, 256, 128, 64, 32, 16, 8, 4, 2, 1};
    static const int bb[12] = {1, 3, 7, 15, 31, 63, 127, 255, 511, 1023, 2047, 4095};
    static const int bmv[12] = {2, 4, 8, 16, 32, 64, 128, 256, 512, 1024, 2048, 1};

    for (int l = 0; l < 2; ++l) {
        prep_layer<<<dim3(5530), 256, 0, stream>>>(
            fw_Wp + (size_t)l * 512 * 1024,  fw_Wx + (size_t)l * 3072 * 1024,
            bw_Wp + (size_t)l * 512 * 1024,  bw_Wx + (size_t)l * 2560 * 1024,
            fw_Wl + (size_t)l * 3072 * 512,  fw_Wr + (size_t)l * 3072 * 512,
            bw_Wh + (size_t)l * 2560 * 512,
            fw_bp + (size_t)l * 512, fw_bx + (size_t)l * 3072,
            bw_bp + (size_t)l * 512, bw_bx + (size_t)l * 2560,
            Wcat, Wlr, Wh, biascat);

        // fused precompute: PX[4096][6656] = A @ [Wp_f|Wx_f|Wp_b|Wx_b]^T + bias
        const f16* A16 = (l == 0) ? feat16 : H;
        mm_pre8<<<dim3(NCAT / 256, 4096 / 256), 512, 0, stream>>>(
            A16, Wcat, biascat, PX, NCAT, 1024);

        float* o32 = (l == 1) ? (float*)d_out : nullptr;
        const float* bl_l = fw_bl + (size_t)l * 3072;
        const float* br_l = fw_br + (size_t)l * 3072;
        const float* bh_l = bw_bh + (size_t)l * 2560;

        // merged leaves (fwd, m=2048) + root (bwd, m=1): no GEMM needed
        {
            int tot = (2048 + 1) * 64;
            elem_merged<<<dim3((tot + 255) / 256), 256, 0, stream>>>(
                PX, 2048, 2048, 0, 1,
                lc, rc, par, cbf, cbb, H, o32, bl_l, br_l, bh_l);
        }
        for (int i = 0; i < 12; ++i) {
            int nfB = ((fmv[i] + 127) >> 7) * 32;
            int nbB = ((bmv[i] + 127) >> 7) * 32;
            stage_fused<<<dim3(nfB + nbB), 256, 0, stream>>>(
                Wlr, Wh, H, PX, lc, rc, par,
                fb[i], fmv[i], bb[i], bmv[i],
                cbf, cbb, o32, bl_l, br_l, bh_l);
        }
    }
    // layer-1 stage/elem kernels wrote d_out directly; nothing else to copy
}